// Round 4
// baseline (145.510 us; speedup 1.0000x reference)
//
#include <hip/hip_runtime.h>
#include <hip/hip_bf16.h>
#include <stdint.h>

// B=16, K=8, N=196, D=768, H=3072, DOUT=768
// y[b,n,:] = (mean_k relu(slots[b,k]@W1 + pos[n]@W1 + b1)) @ W2 + b2
// (softmax over K of K-identical values is exactly 1/K; map_alpha unused)
//
// GEMM operands are pre-tiled into 64x64 "atoms" matching the LDS image:
//   atom = [kb 0..7][r 0..63] chunks of 8 bf16; elem off = atom_base + (kb*64+r)*8.
// gemm_tiled: BM=64 x BN=128 (two B atoms), BK=64, double-buffered
// global_load_lds pipeline with fine vmcnt, split-K via blockIdx.z + f32
// atomicAdd epilogue (outputs pre-initialized: C1=0, out=b2).

typedef __attribute__((ext_vector_type(8))) short bf16x8;
typedef __attribute__((ext_vector_type(4))) float f32x4;

#define AS1 __attribute__((address_space(1)))
#define AS3 __attribute__((address_space(3)))

#define WAIT_VM(N) asm volatile("s_waitcnt vmcnt(" #N ")" ::: "memory")
#define BAR()      asm volatile("s_barrier" ::: "memory")
#define BAR_LDS()  asm volatile("s_waitcnt lgkmcnt(0)\ns_barrier" ::: "memory")

static __device__ __forceinline__ void gld_lds16(const void* g, void* l) {
    __builtin_amdgcn_global_load_lds((const AS1 unsigned int*)g,
                                     (AS3 unsigned int*)l, 16, 0, 0);
}

static __device__ __forceinline__ unsigned short f2bf(float f) {
    union { float f; unsigned int u; } v; v.f = f;
    unsigned int u = v.u;
    return (unsigned short)((u + 0x7fffu + ((u >> 16) & 1u)) >> 16);  // RNE
}

// ---------------- prep: tiled transposes + A1 pack + C1 zero + out=b2 ----------------
static __device__ __forceinline__ void conv_tiled(const float* __restrict__ W,
                                                  unsigned short* __restrict__ Wt,
                                                  int Kd, int Rd, int idx) {
    int r  = idx % Rd;                 // consecutive tid -> consecutive r (coalesced)
    int kc = idx / Rd;                 // 8-elem k-chunk
    unsigned int po[4];
    #pragma unroll
    for (int j = 0; j < 4; ++j) {
        unsigned short lo = f2bf(W[(size_t)(kc * 8 + 2 * j) * Rd + r]);
        unsigned short hi = f2bf(W[(size_t)(kc * 8 + 2 * j + 1) * Rd + r]);
        po[j] = (unsigned int)lo | ((unsigned int)hi << 16);
    }
    size_t dst = ((size_t)(r >> 6) * (Kd >> 6) + (kc >> 3)) * 4096
               + (size_t)((kc & 7) * 64 + (r & 63)) * 8;
    *(uint4*)(Wt + dst) = make_uint4(po[0], po[1], po[2], po[3]);
}

__global__ void k_prep(const float* __restrict__ W1, unsigned short* __restrict__ W1t,
                       const float* __restrict__ W2, unsigned short* __restrict__ W2t,
                       const float* __restrict__ S, const float* __restrict__ P,
                       unsigned short* __restrict__ A1,
                       float* __restrict__ C1, const float* __restrict__ b2,
                       float* __restrict__ out) {
    int idx = blockIdx.x * blockDim.x + threadIdx.x;
    const int T1 = 96 * 3072;      // 294912 W1t
    const int T2 = 384 * 768;      // 294912 W2t
    const int T3 = 96 * 384;       //  36864 A1 pack
    const int T4 = 384 * 3072 / 4; // 294912 C1 zero (float4)
    const int T5 = 3136 * 768 / 4; // 602112 out = b2 (float4)
    if (idx < T1) { conv_tiled(W1, W1t, 768, 3072, idx); return; }
    idx -= T1;
    if (idx < T2) { conv_tiled(W2, W2t, 3072, 768, idx); return; }
    idx -= T2;
    if (idx < T3) {
        int r  = idx % 384;
        int kc = idx / 384;
        uint4 o = make_uint4(0u, 0u, 0u, 0u);
        if (r < 324) {
            const float* src = (r < 128) ? (S + (size_t)r * 768 + kc * 8)
                                         : (P + (size_t)(r - 128) * 768 + kc * 8);
            float4 a = *(const float4*)(src);
            float4 b = *(const float4*)(src + 4);
            o.x = (unsigned int)f2bf(a.x) | ((unsigned int)f2bf(a.y) << 16);
            o.y = (unsigned int)f2bf(a.z) | ((unsigned int)f2bf(a.w) << 16);
            o.z = (unsigned int)f2bf(b.x) | ((unsigned int)f2bf(b.y) << 16);
            o.w = (unsigned int)f2bf(b.z) | ((unsigned int)f2bf(b.w) << 16);
        }
        size_t dst = ((size_t)(r >> 6) * 12 + (kc >> 3)) * 4096
                   + (size_t)((kc & 7) * 64 + (r & 63)) * 8;
        *(uint4*)(A1 + dst) = o;
        return;
    }
    idx -= T3;
    if (idx < T4) { *(float4*)(C1 + (size_t)idx * 4) = make_float4(0.f, 0.f, 0.f, 0.f); return; }
    idx -= T4;
    if (idx < T5) {
        int m = idx / 192;
        int r = idx - m * 192;
        *(float4*)(out + (size_t)m * 768 + r * 4) = *(const float4*)(b2 + r * 4);
    }
}

// ---- hbar: one wave = 64 consecutive bn x 8 h; writes GEMM2's tiled A layout ----
__global__ void k_hbar(const float* __restrict__ C1, const float* __restrict__ b1,
                       unsigned short* __restrict__ Hb) {
    const int lane = threadIdx.x & 63;
    const int wv   = threadIdx.x >> 6;
    const int hc   = blockIdx.y * 4 + wv;          // 0..383
    const int h0   = hc * 8;
    const int bn   = blockIdx.x * 64 + lane;       // 0..3135
    const int b    = bn / 196;
    const int n    = bn - b * 196;
    const float* prow = C1 + (size_t)(128 + n) * 3072 + h0;
    float4 pA = *(const float4*)(prow);
    float4 pB = *(const float4*)(prow + 4);
    float4 bA = *(const float4*)(b1 + h0);
    float4 bB = *(const float4*)(b1 + h0 + 4);
    float pb[8] = { pA.x + bA.x, pA.y + bA.y, pA.z + bA.z, pA.w + bA.w,
                    pB.x + bB.x, pB.y + bB.y, pB.z + bB.z, pB.w + bB.w };
    float acc[8] = {};
    #pragma unroll
    for (int k = 0; k < 8; ++k) {
        const float* srow = C1 + (size_t)(b * 8 + k) * 3072 + h0;  // wave-broadcast
        float4 sA_ = *(const float4*)(srow);
        float4 sB_ = *(const float4*)(srow + 4);
        acc[0] += fmaxf(sA_.x + pb[0], 0.f);
        acc[1] += fmaxf(sA_.y + pb[1], 0.f);
        acc[2] += fmaxf(sA_.z + pb[2], 0.f);
        acc[3] += fmaxf(sA_.w + pb[3], 0.f);
        acc[4] += fmaxf(sB_.x + pb[4], 0.f);
        acc[5] += fmaxf(sB_.y + pb[5], 0.f);
        acc[6] += fmaxf(sB_.z + pb[6], 0.f);
        acc[7] += fmaxf(sB_.w + pb[7], 0.f);
    }
    unsigned int w0 = (unsigned int)f2bf(acc[0] * 0.125f) | ((unsigned int)f2bf(acc[1] * 0.125f) << 16);
    unsigned int w1 = (unsigned int)f2bf(acc[2] * 0.125f) | ((unsigned int)f2bf(acc[3] * 0.125f) << 16);
    unsigned int w2 = (unsigned int)f2bf(acc[4] * 0.125f) | ((unsigned int)f2bf(acc[5] * 0.125f) << 16);
    unsigned int w3 = (unsigned int)f2bf(acc[6] * 0.125f) | ((unsigned int)f2bf(acc[7] * 0.125f) << 16);
    size_t dst = ((size_t)blockIdx.x * 48 + (hc >> 3)) * 4096
               + (size_t)((hc & 7) * 64 + lane) * 8;
    *(uint4*)(Hb + dst) = make_uint4(w0, w1, w2, w3);
}

// ---- tiled bf16 MFMA GEMM: BM=64, BN=128, BK=64, split-K, atomic epilogue ----
// A tiled [rt][aKT][4096]; Bt tiled [rowAtom][bKT][4096] (col-tile nt = atoms 2nt,2nt+1).
// grid = (Nd/128, Mtiles, splits); each split covers ktPer k-atoms starting z*ktPer.
__launch_bounds__(256)
__global__ void gemm_tiled(const unsigned short* __restrict__ A,
                           const unsigned short* __restrict__ Bt,
                           float* __restrict__ C,
                           int Mstore, int Nd, int aKT, int bKT, int ktPer) {
    __shared__ unsigned short smem[2 * 12288];   // [buf][A 4096 | B0 4096 | B1 4096]

    const int tid  = threadIdx.x;
    const int lane = tid & 63;
    const int wave = tid >> 6;
    const int wm   = wave >> 1;          // M half (0..1)
    const int wn   = wave & 1;           // N half / B atom (0..1)
    const int q    = lane >> 4;
    const int l16  = lane & 15;
    const int nt   = blockIdx.x;
    const int rt   = blockIdx.y;
    const int kt0  = blockIdx.z * ktPer;

    const unsigned short* Ab = A  + ((size_t)rt * aKT + kt0) * 4096;
    const unsigned short* B0 = Bt + ((size_t)(2 * nt)     * bKT + kt0) * 4096;
    const unsigned short* B1 = Bt + ((size_t)(2 * nt + 1) * bKT + kt0) * 4096;

    f32x4 acc[2][4] = {};

    auto stage = [&](int i, unsigned short* dst) {   // 6 gld_lds16 per wave
        const unsigned short* Ag  = Ab + (size_t)i * 4096;
        const unsigned short* Bg0 = B0 + (size_t)i * 4096;
        const unsigned short* Bg1 = B1 + (size_t)i * 4096;
        gld_lds16(Ag  + tid * 8,         dst + tid * 8);
        gld_lds16(Ag  + 2048 + tid * 8,  dst + 2048 + tid * 8);
        gld_lds16(Bg0 + tid * 8,         dst + 4096 + tid * 8);
        gld_lds16(Bg0 + 2048 + tid * 8,  dst + 6144 + tid * 8);
        gld_lds16(Bg1 + tid * 8,         dst + 8192 + tid * 8);
        gld_lds16(Bg1 + 2048 + tid * 8,  dst + 10240 + tid * 8);
    };

    const int offA = (wm * 32 + l16) * 8;            // + (ks*4+q)*512 + ii*128
    const int offB = 4096 + wn * 4096 + l16 * 8;     // + (ks*4+q)*512 + jj*128

    auto compute = [&](const unsigned short* buf) {
        #pragma unroll
        for (int ks = 0; ks < 2; ++ks) {
            const int kb = (ks * 4 + q) * 512;
            bf16x8 af[2], bfr[4];
            af[0]  = *(const bf16x8*)(buf + kb + offA);
            af[1]  = *(const bf16x8*)(buf + kb + offA + 128);
            const unsigned short* bb = buf + kb + offB;
            bfr[0] = *(const bf16x8*)(bb);
            bfr[1] = *(const bf16x8*)(bb + 128);
            bfr[2] = *(const bf16x8*)(bb + 256);
            bfr[3] = *(const bf16x8*)(bb + 384);
            #pragma unroll
            for (int ii = 0; ii < 2; ++ii)
                #pragma unroll
                for (int jj = 0; jj < 4; ++jj)
                    acc[ii][jj] = __builtin_amdgcn_mfma_f32_16x16x32_bf16(
                        af[ii], bfr[jj], acc[ii][jj], 0, 0, 0);
        }
    };

    stage(0, smem);
    for (int i = 0; i < ktPer; i += 2) {   // ktPer even
        if (i + 1 < ktPer) { stage(i + 1, smem + 12288); WAIT_VM(6); }
        else               { WAIT_VM(0); }
        BAR();
        compute(smem);
        BAR_LDS();
        if (i + 2 < ktPer) { stage(i + 2, smem); WAIT_VM(6); }
        else               { WAIT_VM(0); }
        BAR();
        compute(smem + 12288);
        if (i + 2 < ktPer) BAR_LDS();
    }

    // epilogue: C/D col=lane&15, row=(lane>>4)*4+reg; split-K partial -> atomicAdd
    const int row0 = rt * 64 + wm * 32;
    const int col0 = nt * 128 + wn * 64;
    #pragma unroll
    for (int ii = 0; ii < 2; ++ii) {
        #pragma unroll
        for (int jj = 0; jj < 4; ++jj) {
            int col = col0 + jj * 16 + l16;
            #pragma unroll
            for (int r = 0; r < 4; ++r) {
                int row = row0 + ii * 16 + q * 4 + r;
                if (row < Mstore) atomicAdd(&C[(size_t)row * Nd + col], acc[ii][jj][r]);
            }
        }
    }
}

extern "C" void kernel_launch(void* const* d_in, const int* in_sizes, int n_in,
                              void* d_out, int out_size, void* d_ws, size_t ws_size,
                              hipStream_t stream) {
    const float* slots  = (const float*)d_in[0];   // 16*8*768
    const float* pos    = (const float*)d_in[1];   // 196*768
    // d_in[2] = map_alpha: unused (softmax over K of identical values = 1/K)
    const float* W1     = (const float*)d_in[3];   // 768*3072
    const float* b1     = (const float*)d_in[4];   // 3072
    const float* W2     = (const float*)d_in[5];   // 3072*768
    const float* b2     = (const float*)d_in[6];   // 768
    float* out = (float*)d_out;                    // 3136*768 f32

    size_t off = 0;
    auto alloc = [&](size_t bytes) {
        void* p = (char*)d_ws + off;
        off += (bytes + 255) & ~(size_t)255;
        return p;
    };
    unsigned short* W1t = (unsigned short*)alloc((size_t)3072 * 768 * 2);   // [48][12] atoms
    unsigned short* W2t = (unsigned short*)alloc((size_t)768 * 3072 * 2);   // [12][48] atoms
    unsigned short* A1  = (unsigned short*)alloc((size_t)384 * 768 * 2);    // [6][12] atoms
    float*          C1  = (float*)alloc((size_t)384 * 3072 * 4);            // row-major
    unsigned short* Hb  = (unsigned short*)alloc((size_t)3136 * 3072 * 2);  // [49][48] atoms

    // 1) prep: transposes + pack + C1=0 + out=b2  (1,523,712 tasks)
    k_prep<<<5952, 256, 0, stream>>>(W1, W1t, W2, W2t, slots, pos, A1, C1, b2, out);
    // 2) C1 += A1 @ W1t^T  (324x3072, K=768; split-K x2 -> 288 blocks, KT=6)
    gemm_tiled<<<dim3(24, 6, 2), 256, 0, stream>>>(A1, W1t, C1, 324, 3072, 12, 12, 6);
    // 3) hbar -> Hb (tiled A layout for GEMM2)
    k_hbar<<<dim3(49, 96), 256, 0, stream>>>(C1, b1, Hb);
    // 4) out += Hb @ W2t^T  (3136x768, K=3072; split-K x2 -> 588 blocks, KT=24)
    gemm_tiled<<<dim3(6, 49, 2), 256, 0, stream>>>(Hb, W2t, out, 3136, 768, 48, 48, 24);
}